// Round 8
// baseline (181.277 us; speedup 1.0000x reference)
//
#include <hip/hip_runtime.h>

// Problem dims (fixed by reference)
#define BATCH  4096
#define IN_DIM 256
#define HID    512
#define NCOL   8192            // HID * STATES

// Main tiling: 128x64 block tile, 4 waves stacked on M (32 rows each)
#define BM 128
#define BN 64

typedef __attribute__((ext_vector_type(8))) short bf16x8;
typedef __attribute__((ext_vector_type(4))) float f32x4;
typedef __attribute__((ext_vector_type(4))) float fvec4;   // clang-native, nt-compatible

// pack bf16(f0) into low16, bf16(f1) into high16 (truncation) — 1 v_perm_b32
__device__ __forceinline__ uint pack_hi(float f0, float f1) {
    return __builtin_amdgcn_perm(__builtin_bit_cast(uint, f1),
                                 __builtin_bit_cast(uint, f0), 0x07060302u);
}
__device__ __forceinline__ float hi_part(float f) {
    return __builtin_bit_cast(float, __builtin_bit_cast(uint, f) & 0xFFFF0000u);
}
__device__ __forceinline__ float tanh_fast(float x) {
    float e = __builtin_amdgcn_exp2f(x * 2.8853900817779268f); // 2*log2(e)
    float r = __builtin_amdgcn_rcpf(e + 1.0f);
    return __builtin_fmaf(-2.0f, r, 1.0f);
}
// split f[0..7] (k-consecutive) into hi/lo bf16x8 fragments
__device__ __forceinline__ void split8(const float* f, uint4& h, uint4& l) {
    h.x = pack_hi(f[0], f[1]); h.y = pack_hi(f[2], f[3]);
    h.z = pack_hi(f[4], f[5]); h.w = pack_hi(f[6], f[7]);
    l.x = pack_hi(f[0] - hi_part(f[0]), f[1] - hi_part(f[1]));
    l.y = pack_hi(f[2] - hi_part(f[2]), f[3] - hi_part(f[3]));
    l.z = pack_hi(f[4] - hi_part(f[4]), f[5] - hi_part(f[5]));
    l.w = pack_hi(f[6] - hi_part(f[6]), f[7] - hi_part(f[7]));
}

// Workspace layout (ushort elements):
//  whi [0, 2097152)  wlo [2097152, 4194304)   - 8192n x 256k, tiled
//  xhi [4194304, 5242880) xlo [5242880, 6291456) - 4096b x 256k, tiled
// tile layout: plane[((row>>4)*32 + koct)*128 + (row&15)*8 + j], k = koct*8+j
#define W_ELEMS  2097152
#define X_ELEMS  1048576
#define WS_NEED  (12u * 1024u * 1024u)

// ---- prep W: [k][n] f32 -> fragment-ready tiled bf16 hi/lo ----
__global__ __launch_bounds__(256) void prep_w_kernel(
    const float* __restrict__ W, ushort* __restrict__ whi, ushort* __restrict__ wlo)
{
    const int n    = blockIdx.x * 256 + threadIdx.x;   // 0..8191
    const int koct = blockIdx.y;                       // 0..31
    float f[8];
    #pragma unroll
    for (int j = 0; j < 8; ++j)
        f[j] = __builtin_nontemporal_load(&W[(size_t)(koct * 8 + j) * NCOL + n]);
    uint4 h, l;
    split8(f, h, l);
    const size_t o = ((size_t)((n >> 4) * 32 + koct) * 16 + (n & 15)) * 8;
    *(uint4*)(whi + o) = h;
    *(uint4*)(wlo + o) = l;
}

// ---- prep x: [b][k] f32 -> fragment-ready tiled bf16 hi/lo ----
__global__ __launch_bounds__(256) void prep_x_kernel(
    const float* __restrict__ x, ushort* __restrict__ xhi, ushort* __restrict__ xlo)
{
    const int b    = blockIdx.x * 256 + threadIdx.x;   // 0..4095
    const int koct = blockIdx.y;                       // 0..31
    float f[8];
    fvec4 v0 = __builtin_nontemporal_load((const fvec4*)&x[(size_t)b * IN_DIM + koct * 8]);
    fvec4 v1 = __builtin_nontemporal_load((const fvec4*)&x[(size_t)b * IN_DIM + koct * 8 + 4]);
    f[0] = v0.x; f[1] = v0.y; f[2] = v0.z; f[3] = v0.w;
    f[4] = v1.x; f[5] = v1.y; f[6] = v1.z; f[7] = v1.w;
    uint4 h, l;
    split8(f, h, l);
    const size_t o = ((size_t)((b >> 4) * 32 + koct) * 16 + (b & 15)) * 8;
    *(uint4*)(xhi + o) = h;
    *(uint4*)(xlo + o) = l;
}

// ---- main: zero LDS, zero barriers; load+MFMA, nt streaming epilogue ----
// min-waves-per-EU = 4 (VGPR cap 128): round 4 proved 8 (cap 64) forces
// catastrophic scratch spills (+1.2 GB HBM traffic). Do not raise.
__global__ __launch_bounds__(256, 4) void mqc_main_kernel(
    const ushort* __restrict__ xhi, const ushort* __restrict__ xlo,
    const ushort* __restrict__ whi, const ushort* __restrict__ wlo,
    const float* __restrict__ hq,
    float* __restrict__ out_mean, float* __restrict__ out_new)
{
    const int t     = threadIdx.x;
    const int lane  = t & 63;
    const int w     = t >> 6;           // wave 0..3 -> rows w*32..w*32+31
    const int lquad = lane >> 4;        // 0..3
    const int l16   = lane & 15;

    // XCD-clustered bijective block mapping (4096 = 8 xcd * 4 rowg * 128 colg):
    // the ~4 concurrent blocks on one XCD share a W col-tile -> L2 W hits;
    // per-XCD x slice (4 row-groups, 512 KB) stays L2-resident.
    const int wgid = blockIdx.x;
    const int xcd  = wgid & 7;
    const int q    = wgid >> 3;
    const int rowg = (xcd << 2) | (q & 3);   // 0..31
    const int colg = q >> 2;                 // 0..127
    const int row0 = rowg * BM;
    const int col0 = colg * BN;
    const int btile0 = (row0 >> 4) + w * 2;
    const int ntile0 = col0 >> 4;

    f32x4 acc[2][4] = {};               // [mi][ni]; D[n][b]: row=n, col=b

    #define KSTEP(koct_expr)                                                            \
    {                                                                                   \
        const int koct = (koct_expr);                                                   \
        bf16x8 aH[2], aL[2], bH[4], bL[4];                                              \
        _Pragma("unroll")                                                               \
        for (int mi = 0; mi < 2; ++mi) {                                                \
            const size_t o = ((size_t)((btile0 + mi) * 32 + koct) * 16 + l16) * 8;      \
            aH[mi] = *(const bf16x8*)(xhi + o);                                         \
            aL[mi] = *(const bf16x8*)(xlo + o);                                         \
        }                                                                               \
        _Pragma("unroll")                                                               \
        for (int ni = 0; ni < 4; ++ni) {                                                \
            const size_t o = ((size_t)((ntile0 + ni) * 32 + koct) * 16 + l16) * 8;      \
            bH[ni] = *(const bf16x8*)(whi + o);                                         \
            bL[ni] = *(const bf16x8*)(wlo + o);                                         \
        }                                                                               \
        _Pragma("unroll")                                                               \
        for (int mi = 0; mi < 2; ++mi)                                                  \
            _Pragma("unroll")                                                           \
            for (int ni = 0; ni < 4; ++ni)                                              \
                acc[mi][ni] = __builtin_amdgcn_mfma_f32_16x16x32_bf16(bH[ni], aH[mi], acc[mi][ni], 0, 0, 0); \
        _Pragma("unroll")                                                               \
        for (int mi = 0; mi < 2; ++mi)                                                  \
            _Pragma("unroll")                                                           \
            for (int ni = 0; ni < 4; ++ni)                                              \
                acc[mi][ni] = __builtin_amdgcn_mfma_f32_16x16x32_bf16(bH[ni], aL[mi], acc[mi][ni], 0, 0, 0); \
        _Pragma("unroll")                                                               \
        for (int mi = 0; mi < 2; ++mi)                                                  \
            _Pragma("unroll")                                                           \
            for (int ni = 0; ni < 4; ++ni)                                              \
                acc[mi][ni] = __builtin_amdgcn_mfma_f32_16x16x32_bf16(bL[ni], aH[mi], acc[mi][ni], 0, 0, 0); \
    }

    // k-steps 0..5 (kt 0..2)
    for (int kt = 0; kt < 3; ++kt) {
        #pragma unroll
        for (int ks = 0; ks < 2; ++ks)
            KSTEP(kt * 8 + ks * 4 + lquad);
    }

    // peeled kt=3, ks=0: after its loads, issue the epilogue hq prefetch (nt)
    // so ~72 MFMAs cover the HBM latency.
    fvec4 hv[2][4];
    {
        const int koct = 24 + lquad;
        bf16x8 aH[2], aL[2], bH[4], bL[4];
        #pragma unroll
        for (int mi = 0; mi < 2; ++mi) {
            const size_t o = ((size_t)((btile0 + mi) * 32 + koct) * 16 + l16) * 8;
            aH[mi] = *(const bf16x8*)(xhi + o);
            aL[mi] = *(const bf16x8*)(xlo + o);
        }
        #pragma unroll
        for (int ni = 0; ni < 4; ++ni) {
            const size_t o = ((size_t)((ntile0 + ni) * 32 + koct) * 16 + l16) * 8;
            bH[ni] = *(const bf16x8*)(whi + o);
            bL[ni] = *(const bf16x8*)(wlo + o);
        }
        #pragma unroll
        for (int mi = 0; mi < 2; ++mi) {
            const int b = row0 + w * 32 + mi * 16 + l16;
            #pragma unroll
            for (int ni = 0; ni < 4; ++ni) {
                const int n = col0 + ni * 16 + lquad * 4;
                hv[mi][ni] = __builtin_nontemporal_load((const fvec4*)&hq[(size_t)b * NCOL + n]);
            }
        }
        #pragma unroll
        for (int mi = 0; mi < 2; ++mi)
            #pragma unroll
            for (int ni = 0; ni < 4; ++ni)
                acc[mi][ni] = __builtin_amdgcn_mfma_f32_16x16x32_bf16(bH[ni], aH[mi], acc[mi][ni], 0, 0, 0);
        #pragma unroll
        for (int mi = 0; mi < 2; ++mi)
            #pragma unroll
            for (int ni = 0; ni < 4; ++ni)
                acc[mi][ni] = __builtin_amdgcn_mfma_f32_16x16x32_bf16(bH[ni], aL[mi], acc[mi][ni], 0, 0, 0);
        #pragma unroll
        for (int mi = 0; mi < 2; ++mi)
            #pragma unroll
            for (int ni = 0; ni < 4; ++ni)
                acc[mi][ni] = __builtin_amdgcn_mfma_f32_16x16x32_bf16(bL[ni], aH[mi], acc[mi][ni], 0, 0, 0);
    }
    // peeled kt=3, ks=1
    KSTEP(28 + lquad);
    #undef KSTEP

    // ---- fused epilogue: tanh(C + 0.9*h), nt float4 I/O, s-group mean ----
    // D[n][b]: n = col0 + ni*16 + 4*lquad + reg, b = row0 + w*32 + mi*16 + l16
    #pragma unroll
    for (int mi = 0; mi < 2; ++mi) {
        const int b = row0 + w * 32 + mi * 16 + l16;
        #pragma unroll
        for (int ni = 0; ni < 4; ++ni) {
            const int n = col0 + ni * 16 + lquad * 4;
            fvec4 ov;
            ov.x = tanh_fast(__builtin_fmaf(0.9f, hv[mi][ni].x, acc[mi][ni][0]));
            ov.y = tanh_fast(__builtin_fmaf(0.9f, hv[mi][ni].y, acc[mi][ni][1]));
            ov.z = tanh_fast(__builtin_fmaf(0.9f, hv[mi][ni].z, acc[mi][ni][2]));
            ov.w = tanh_fast(__builtin_fmaf(0.9f, hv[mi][ni].w, acc[mi][ni][3]));
            __builtin_nontemporal_store(ov, (fvec4*)&out_new[(size_t)b * NCOL + n]);
            float s = (ov.x + ov.y) + (ov.z + ov.w);
            s += __shfl_xor(s, 16);
            s += __shfl_xor(s, 32);
            if (lquad == 0)
                __builtin_nontemporal_store(s * 0.0625f,
                                            &out_mean[(size_t)b * HID + (col0 >> 4) + ni]);
        }
    }
}

// ================= fallback (round-5 proven kernel, used if ws too small) ======
#define BKF 64
__device__ __forceinline__ int swz(int row, int byteoff) {
    return byteoff ^ ((((row & 7) ^ ((row >> 3) & 7))) << 4);
}
__global__ __launch_bounds__(256, 4) void mqc_fallback_kernel(
    const float* __restrict__ x, const float* __restrict__ hq,
    const float* __restrict__ W,
    float* __restrict__ out_mean, float* __restrict__ out_new)
{
    __shared__ char sB[2 * BN * BKF * 2];
    char* const sB_hi = sB;
    char* const sB_lo = sB + BN * BKF * 2;
    const int t = threadIdx.x, lane = t & 63, w = t >> 6;
    const int lquad = lane >> 4, l16 = lane & 15;
    const int row0 = blockIdx.x * BM, col0 = blockIdx.y * BN;
    const int k0 = (t >> 4) * 4, n0 = (t & 15) * 4;
    f32x4 acc[2][4] = {};
    for (int kt = 0; kt < IN_DIM / BKF; ++kt) {
        float4 ax[2][2][2];
        #pragma unroll
        for (int mi = 0; mi < 2; ++mi)
            #pragma unroll
            for (int ks = 0; ks < 2; ++ks) {
                const float* p = &x[(size_t)(row0 + w * 32 + mi * 16 + l16) * IN_DIM
                                    + kt * BKF + ks * 32 + lquad * 8];
                ax[mi][ks][0] = *(const float4*)(p);
                ax[mi][ks][1] = *(const float4*)(p + 4);
            }
        float4 wrow[4];
        #pragma unroll
        for (int r = 0; r < 4; ++r)
            wrow[r] = *(const float4*)(&W[(size_t)(kt * BKF + k0 + r) * NCOL + col0 + n0]);
        #pragma unroll
        for (int c = 0; c < 4; ++c) {
            const float f0 = ((const float*)&wrow[0])[c];
            const float f1 = ((const float*)&wrow[1])[c];
            const float f2 = ((const float*)&wrow[2])[c];
            const float f3 = ((const float*)&wrow[3])[c];
            uint2 hv2, lv2;
            hv2.x = pack_hi(f0, f1); hv2.y = pack_hi(f2, f3);
            lv2.x = pack_hi(f0 - hi_part(f0), f1 - hi_part(f1));
            lv2.y = pack_hi(f2 - hi_part(f2), f3 - hi_part(f3));
            const int off = swz(n0 + c, (n0 + c) * (BKF * 2) + k0 * 2);
            *(uint2*)(sB_hi + off) = hv2;
            *(uint2*)(sB_lo + off) = lv2;
        }
        __syncthreads();
        #pragma unroll
        for (int ks = 0; ks < 2; ++ks) {
            bf16x8 aH[2], aL[2];
            #pragma unroll
            for (int mi = 0; mi < 2; ++mi) {
                uint4 h, l;
                split8((const float*)&ax[mi][ks][0], h, l);
                aH[mi] = __builtin_bit_cast(bf16x8, h);
                aL[mi] = __builtin_bit_cast(bf16x8, l);
            }
            const int kb = ks * 64 + lquad * 16;
            bf16x8 bH[4], bL[4];
            #pragma unroll
            for (int ni = 0; ni < 4; ++ni) {
                const int row = ni * 16 + l16;
                bH[ni] = *(const bf16x8*)(sB_hi + swz(row, row * (BKF * 2) + kb));
            }
            #pragma unroll
            for (int mi = 0; mi < 2; ++mi)
                #pragma unroll
                for (int ni = 0; ni < 4; ++ni)
                    acc[mi][ni] = __builtin_amdgcn_mfma_f32_16x16x32_bf16(bH[ni], aH[mi], acc[mi][ni], 0, 0, 0);
            #pragma unroll
            for (int mi = 0; mi < 2; ++mi)
                #pragma unroll
                for (int ni = 0; ni < 4; ++ni)
                    acc[mi][ni] = __builtin_amdgcn_mfma_f32_16x16x32_bf16(bH[ni], aL[mi], acc[mi][ni], 0, 0, 0);
            #pragma unroll
            for (int ni = 0; ni < 4; ++ni) {
                const int row = ni * 16 + l16;
                bL[ni] = *(const bf16x8*)(sB_lo + swz(row, row * (BKF * 2) + kb));
            }
            #pragma unroll
            for (int mi = 0; mi < 2; ++mi)
                #pragma unroll
                for (int ni = 0; ni < 4; ++ni)
                    acc[mi][ni] = __builtin_amdgcn_mfma_f32_16x16x32_bf16(bL[ni], aH[mi], acc[mi][ni], 0, 0, 0);
        }
        __syncthreads();
    }
    #pragma unroll
    for (int mi = 0; mi < 2; ++mi) {
        const int b = row0 + w * 32 + mi * 16 + l16;
        #pragma unroll
        for (int ni = 0; ni < 4; ++ni) {
            const int n = col0 + ni * 16 + lquad * 4;
            const float4 hv = *(const float4*)(&hq[(size_t)b * NCOL + n]);
            float4 ov;
            ov.x = tanh_fast(__builtin_fmaf(0.9f, hv.x, acc[mi][ni][0]));
            ov.y = tanh_fast(__builtin_fmaf(0.9f, hv.y, acc[mi][ni][1]));
            ov.z = tanh_fast(__builtin_fmaf(0.9f, hv.z, acc[mi][ni][2]));
            ov.w = tanh_fast(__builtin_fmaf(0.9f, hv.w, acc[mi][ni][3]));
            *(float4*)(&out_new[(size_t)b * NCOL + n]) = ov;
            float s = (ov.x + ov.y) + (ov.z + ov.w);
            s += __shfl_xor(s, 16);
            s += __shfl_xor(s, 32);
            if (lquad == 0)
                out_mean[(size_t)b * HID + (col0 >> 4) + ni] = s * 0.0625f;
        }
    }
}

extern "C" void kernel_launch(void* const* d_in, const int* in_sizes, int n_in,
                              void* d_out, int out_size, void* d_ws, size_t ws_size,
                              hipStream_t stream) {
    const float* x  = (const float*)d_in[0];   // [4096, 256]
    const float* hq = (const float*)d_in[1];   // [4096, 512, 16]
    const float* W  = (const float*)d_in[2];   // [256, 512, 16]

    float* out_mean = (float*)d_out;                          // [4096, 512]
    float* out_new  = (float*)d_out + (size_t)BATCH * HID;    // [4096, 512, 16]

    if (ws_size >= WS_NEED) {
        ushort* whi = (ushort*)d_ws;
        ushort* wlo = whi + W_ELEMS;
        ushort* xhi = wlo + W_ELEMS;
        ushort* xlo = xhi + X_ELEMS;
        prep_w_kernel<<<dim3(NCOL / 256, IN_DIM / 8), 256, 0, stream>>>(W, whi, wlo);
        prep_x_kernel<<<dim3(BATCH / 256, IN_DIM / 8), 256, 0, stream>>>(x, xhi, xlo);
        mqc_main_kernel<<<dim3(BATCH * NCOL / (BM * BN)), 256, 0, stream>>>(
            xhi, xlo, whi, wlo, hq, out_mean, out_new);
    } else {
        mqc_fallback_kernel<<<dim3(BATCH / BM, NCOL / BN), 256, 0, stream>>>(
            x, hq, W, out_mean, out_new);
    }
}

// Round 9
// 165.404 us; speedup vs baseline: 1.0960x; 1.0960x over previous
//
#include <hip/hip_runtime.h>

// Problem dims (fixed by reference)
#define BATCH  4096
#define IN_DIM 256
#define HID    512
#define NCOL   8192            // HID * STATES

// Main tiling: 128x64 block tile, 4 waves stacked on M (32 rows each)
#define BM 128
#define BN 64

typedef __attribute__((ext_vector_type(8))) short bf16x8;
typedef __attribute__((ext_vector_type(4))) float f32x4;
typedef __attribute__((ext_vector_type(4))) float fvec4;   // clang-native, nt-compatible

// pack bf16(f0) into low16, bf16(f1) into high16 (truncation) — 1 v_perm_b32
__device__ __forceinline__ uint pack_hi(float f0, float f1) {
    return __builtin_amdgcn_perm(__builtin_bit_cast(uint, f1),
                                 __builtin_bit_cast(uint, f0), 0x07060302u);
}
__device__ __forceinline__ float hi_part(float f) {
    return __builtin_bit_cast(float, __builtin_bit_cast(uint, f) & 0xFFFF0000u);
}
__device__ __forceinline__ float tanh_fast(float x) {
    float e = __builtin_amdgcn_exp2f(x * 2.8853900817779268f); // 2*log2(e)
    float r = __builtin_amdgcn_rcpf(e + 1.0f);
    return __builtin_fmaf(-2.0f, r, 1.0f);
}
// split f[0..7] (k-consecutive) into hi/lo bf16x8 fragments
__device__ __forceinline__ void split8(const float* f, uint4& h, uint4& l) {
    h.x = pack_hi(f[0], f[1]); h.y = pack_hi(f[2], f[3]);
    h.z = pack_hi(f[4], f[5]); h.w = pack_hi(f[6], f[7]);
    l.x = pack_hi(f[0] - hi_part(f[0]), f[1] - hi_part(f[1]));
    l.y = pack_hi(f[2] - hi_part(f[2]), f[3] - hi_part(f[3]));
    l.z = pack_hi(f[4] - hi_part(f[4]), f[5] - hi_part(f[5]));
    l.w = pack_hi(f[6] - hi_part(f[6]), f[7] - hi_part(f[7]));
}

// Workspace layout (ushort elements):
//  whi [0, 2097152)  wlo [2097152, 4194304)   - 8192n x 256k, tiled
//  xhi [4194304, 5242880) xlo [5242880, 6291456) - 4096b x 256k, tiled
// tile layout: plane[((row>>4)*32 + koct)*128 + (row&15)*8 + j], k = koct*8+j
#define W_ELEMS  2097152
#define X_ELEMS  1048576
#define WS_NEED  (12u * 1024u * 1024u)

// ---- prep W: [k][n] f32 -> fragment-ready tiled bf16 hi/lo ----
__global__ __launch_bounds__(256) void prep_w_kernel(
    const float* __restrict__ W, ushort* __restrict__ whi, ushort* __restrict__ wlo)
{
    const int n    = blockIdx.x * 256 + threadIdx.x;   // 0..8191
    const int koct = blockIdx.y;                       // 0..31
    float f[8];
    #pragma unroll
    for (int j = 0; j < 8; ++j)
        f[j] = __builtin_nontemporal_load(&W[(size_t)(koct * 8 + j) * NCOL + n]);
    uint4 h, l;
    split8(f, h, l);
    const size_t o = ((size_t)((n >> 4) * 32 + koct) * 16 + (n & 15)) * 8;
    *(uint4*)(whi + o) = h;
    *(uint4*)(wlo + o) = l;
}

// ---- prep x: [b][k] f32 -> fragment-ready tiled bf16 hi/lo ----
__global__ __launch_bounds__(256) void prep_x_kernel(
    const float* __restrict__ x, ushort* __restrict__ xhi, ushort* __restrict__ xlo)
{
    const int b    = blockIdx.x * 256 + threadIdx.x;   // 0..4095
    const int koct = blockIdx.y;                       // 0..31
    float f[8];
    fvec4 v0 = __builtin_nontemporal_load((const fvec4*)&x[(size_t)b * IN_DIM + koct * 8]);
    fvec4 v1 = __builtin_nontemporal_load((const fvec4*)&x[(size_t)b * IN_DIM + koct * 8 + 4]);
    f[0] = v0.x; f[1] = v0.y; f[2] = v0.z; f[3] = v0.w;
    f[4] = v1.x; f[5] = v1.y; f[6] = v1.z; f[7] = v1.w;
    uint4 h, l;
    split8(f, h, l);
    const size_t o = ((size_t)((b >> 4) * 32 + koct) * 16 + (b & 15)) * 8;
    *(uint4*)(xhi + o) = h;
    *(uint4*)(xlo + o) = l;
}

// ---- main: zero LDS, zero barriers; 1-deep pipelined load+MFMA ----
// min-waves-per-EU = 4 (VGPR cap 128): round 4 proved 8 (cap 64) forces
// catastrophic scratch spills (+1.2 GB HBM traffic). Do not raise.
// out_mean store must stay CACHED (nt on 4B scalars caused ~8-16x write
// amplification in round 8: WRITE_SIZE 152->275 MB). Do not nt it.
__global__ __launch_bounds__(256, 4) void mqc_main_kernel(
    const ushort* __restrict__ xhi, const ushort* __restrict__ xlo,
    const ushort* __restrict__ whi, const ushort* __restrict__ wlo,
    const float* __restrict__ hq,
    float* __restrict__ out_mean, float* __restrict__ out_new)
{
    const int t     = threadIdx.x;
    const int lane  = t & 63;
    const int w     = t >> 6;           // wave 0..3 -> rows w*32..w*32+31
    const int lquad = lane >> 4;        // 0..3
    const int l16   = lane & 15;

    // XCD-clustered bijective block mapping (4096 = 8 xcd * 4 rowg * 128 colg)
    const int wgid = blockIdx.x;
    const int xcd  = wgid & 7;
    const int q    = wgid >> 3;
    const int rowg = (xcd << 2) | (q & 3);   // 0..31
    const int colg = q >> 2;                 // 0..127
    const int row0 = rowg * BM;
    const int col0 = colg * BN;
    const int btile0 = (row0 >> 4) + w * 2;
    const int ntile0 = col0 >> 4;

    f32x4 acc[2][4] = {};               // [mi][ni]; D[n][b]: row=n, col=b

    // two named fragment buffers, 1-deep software pipeline
    bf16x8 AH0[2], AL0[2], BH0[4], BL0[4];
    bf16x8 AH1[2], AL1[2], BH1[4], BL1[4];

    #define PREF(AH, AL, BH, BL, KOCT) {                                            \
        const int koct_ = (KOCT);                                                   \
        _Pragma("unroll")                                                           \
        for (int mi = 0; mi < 2; ++mi) {                                            \
            const size_t o = ((size_t)((btile0 + mi) * 32 + koct_) * 16 + l16) * 8; \
            AH[mi] = *(const bf16x8*)(xhi + o);                                     \
            AL[mi] = *(const bf16x8*)(xlo + o);                                     \
        }                                                                           \
        _Pragma("unroll")                                                           \
        for (int ni = 0; ni < 4; ++ni) {                                            \
            const size_t o = ((size_t)((ntile0 + ni) * 32 + koct_) * 16 + l16) * 8; \
            BH[ni] = *(const bf16x8*)(whi + o);                                     \
            BL[ni] = *(const bf16x8*)(wlo + o);                                     \
        }                                                                           \
    }
    // 3-pass: Wh*xh + Wh*xl + Wl*xh  (A-operand = W -> D rows = n)
    #define MFMA3(AH, AL, BH, BL) {                                                 \
        _Pragma("unroll")                                                           \
        for (int mi = 0; mi < 2; ++mi)                                              \
            _Pragma("unroll")                                                       \
            for (int ni = 0; ni < 4; ++ni)                                          \
                acc[mi][ni] = __builtin_amdgcn_mfma_f32_16x16x32_bf16(BH[ni], AH[mi], acc[mi][ni], 0, 0, 0); \
        _Pragma("unroll")                                                           \
        for (int mi = 0; mi < 2; ++mi)                                              \
            _Pragma("unroll")                                                       \
            for (int ni = 0; ni < 4; ++ni)                                          \
                acc[mi][ni] = __builtin_amdgcn_mfma_f32_16x16x32_bf16(BH[ni], AL[mi], acc[mi][ni], 0, 0, 0); \
        _Pragma("unroll")                                                           \
        for (int mi = 0; mi < 2; ++mi)                                              \
            _Pragma("unroll")                                                       \
            for (int ni = 0; ni < 4; ++ni)                                          \
                acc[mi][ni] = __builtin_amdgcn_mfma_f32_16x16x32_bf16(BL[ni], AH[mi], acc[mi][ni], 0, 0, 0); \
    }

    // koct for step s is s*4 + lquad, s = 0..7
    PREF(AH0, AL0, BH0, BL0,  0 + lquad);
    PREF(AH1, AL1, BH1, BL1,  4 + lquad);
    MFMA3(AH0, AL0, BH0, BL0);  PREF(AH0, AL0, BH0, BL0,  8 + lquad);
    MFMA3(AH1, AL1, BH1, BL1);  PREF(AH1, AL1, BH1, BL1, 12 + lquad);
    MFMA3(AH0, AL0, BH0, BL0);  PREF(AH0, AL0, BH0, BL0, 16 + lquad);
    MFMA3(AH1, AL1, BH1, BL1);  PREF(AH1, AL1, BH1, BL1, 20 + lquad);
    MFMA3(AH0, AL0, BH0, BL0);  PREF(AH0, AL0, BH0, BL0, 24 + lquad);
    MFMA3(AH1, AL1, BH1, BL1);  PREF(AH1, AL1, BH1, BL1, 28 + lquad);
    MFMA3(AH0, AL0, BH0, BL0);
    MFMA3(AH1, AL1, BH1, BL1);
    #undef PREF
    #undef MFMA3

    // ---- fused epilogue: tanh(C + 0.9*h), nt hq load + nt out_new store,
    //      CACHED out_mean store. D[n][b]: n = col0+ni*16+4*lquad+reg,
    //      b = row0+w*32+mi*16+l16
    #pragma unroll
    for (int mi = 0; mi < 2; ++mi) {
        const int b = row0 + w * 32 + mi * 16 + l16;
        #pragma unroll
        for (int ni = 0; ni < 4; ++ni) {
            const int n = col0 + ni * 16 + lquad * 4;
            const fvec4 hv = __builtin_nontemporal_load((const fvec4*)&hq[(size_t)b * NCOL + n]);
            fvec4 ov;
            ov.x = tanh_fast(__builtin_fmaf(0.9f, hv.x, acc[mi][ni][0]));
            ov.y = tanh_fast(__builtin_fmaf(0.9f, hv.y, acc[mi][ni][1]));
            ov.z = tanh_fast(__builtin_fmaf(0.9f, hv.z, acc[mi][ni][2]));
            ov.w = tanh_fast(__builtin_fmaf(0.9f, hv.w, acc[mi][ni][3]));
            __builtin_nontemporal_store(ov, (fvec4*)&out_new[(size_t)b * NCOL + n]);
            float s = (ov.x + ov.y) + (ov.z + ov.w);
            s += __shfl_xor(s, 16);
            s += __shfl_xor(s, 32);
            if (lquad == 0)
                out_mean[(size_t)b * HID + (col0 >> 4) + ni] = s * 0.0625f;
        }
    }
}

// ================= fallback (round-5 proven kernel, used if ws too small) ======
#define BKF 64
__device__ __forceinline__ int swz(int row, int byteoff) {
    return byteoff ^ ((((row & 7) ^ ((row >> 3) & 7))) << 4);
}
__global__ __launch_bounds__(256, 4) void mqc_fallback_kernel(
    const float* __restrict__ x, const float* __restrict__ hq,
    const float* __restrict__ W,
    float* __restrict__ out_mean, float* __restrict__ out_new)
{
    __shared__ char sB[2 * BN * BKF * 2];
    char* const sB_hi = sB;
    char* const sB_lo = sB + BN * BKF * 2;
    const int t = threadIdx.x, lane = t & 63, w = t >> 6;
    const int lquad = lane >> 4, l16 = lane & 15;
    const int row0 = blockIdx.x * BM, col0 = blockIdx.y * BN;
    const int k0 = (t >> 4) * 4, n0 = (t & 15) * 4;
    f32x4 acc[2][4] = {};
    for (int kt = 0; kt < IN_DIM / BKF; ++kt) {
        float4 ax[2][2][2];
        #pragma unroll
        for (int mi = 0; mi < 2; ++mi)
            #pragma unroll
            for (int ks = 0; ks < 2; ++ks) {
                const float* p = &x[(size_t)(row0 + w * 32 + mi * 16 + l16) * IN_DIM
                                    + kt * BKF + ks * 32 + lquad * 8];
                ax[mi][ks][0] = *(const float4*)(p);
                ax[mi][ks][1] = *(const float4*)(p + 4);
            }
        float4 wrow[4];
        #pragma unroll
        for (int r = 0; r < 4; ++r)
            wrow[r] = *(const float4*)(&W[(size_t)(kt * BKF + k0 + r) * NCOL + col0 + n0]);
        #pragma unroll
        for (int c = 0; c < 4; ++c) {
            const float f0 = ((const float*)&wrow[0])[c];
            const float f1 = ((const float*)&wrow[1])[c];
            const float f2 = ((const float*)&wrow[2])[c];
            const float f3 = ((const float*)&wrow[3])[c];
            uint2 hv2, lv2;
            hv2.x = pack_hi(f0, f1); hv2.y = pack_hi(f2, f3);
            lv2.x = pack_hi(f0 - hi_part(f0), f1 - hi_part(f1));
            lv2.y = pack_hi(f2 - hi_part(f2), f3 - hi_part(f3));
            const int off = swz(n0 + c, (n0 + c) * (BKF * 2) + k0 * 2);
            *(uint2*)(sB_hi + off) = hv2;
            *(uint2*)(sB_lo + off) = lv2;
        }
        __syncthreads();
        #pragma unroll
        for (int ks = 0; ks < 2; ++ks) {
            bf16x8 aH[2], aL[2];
            #pragma unroll
            for (int mi = 0; mi < 2; ++mi) {
                uint4 h, l;
                split8((const float*)&ax[mi][ks][0], h, l);
                aH[mi] = __builtin_bit_cast(bf16x8, h);
                aL[mi] = __builtin_bit_cast(bf16x8, l);
            }
            const int kb = ks * 64 + lquad * 16;
            bf16x8 bH[4], bL[4];
            #pragma unroll
            for (int ni = 0; ni < 4; ++ni) {
                const int row = ni * 16 + l16;
                bH[ni] = *(const bf16x8*)(sB_hi + swz(row, row * (BKF * 2) + kb));
            }
            #pragma unroll
            for (int mi = 0; mi < 2; ++mi)
                #pragma unroll
                for (int ni = 0; ni < 4; ++ni)
                    acc[mi][ni] = __builtin_amdgcn_mfma_f32_16x16x32_bf16(bH[ni], aH[mi], acc[mi][ni], 0, 0, 0);
            #pragma unroll
            for (int mi = 0; mi < 2; ++mi)
                #pragma unroll
                for (int ni = 0; ni < 4; ++ni)
                    acc[mi][ni] = __builtin_amdgcn_mfma_f32_16x16x32_bf16(bH[ni], aL[mi], acc[mi][ni], 0, 0, 0);
            #pragma unroll
            for (int ni = 0; ni < 4; ++ni) {
                const int row = ni * 16 + l16;
                bL[ni] = *(const bf16x8*)(sB_lo + swz(row, row * (BKF * 2) + kb));
            }
            #pragma unroll
            for (int mi = 0; mi < 2; ++mi)
                #pragma unroll
                for (int ni = 0; ni < 4; ++ni)
                    acc[mi][ni] = __builtin_amdgcn_mfma_f32_16x16x32_bf16(bL[ni], aH[mi], acc[mi][ni], 0, 0, 0);
        }
        __syncthreads();
    }
    #pragma unroll
    for (int mi = 0; mi < 2; ++mi) {
        const int b = row0 + w * 32 + mi * 16 + l16;
        #pragma unroll
        for (int ni = 0; ni < 4; ++ni) {
            const int n = col0 + ni * 16 + lquad * 4;
            const float4 hv = *(const float4*)(&hq[(size_t)b * NCOL + n]);
            float4 ov;
            ov.x = tanh_fast(__builtin_fmaf(0.9f, hv.x, acc[mi][ni][0]));
            ov.y = tanh_fast(__builtin_fmaf(0.9f, hv.y, acc[mi][ni][1]));
            ov.z = tanh_fast(__builtin_fmaf(0.9f, hv.z, acc[mi][ni][2]));
            ov.w = tanh_fast(__builtin_fmaf(0.9f, hv.w, acc[mi][ni][3]));
            *(float4*)(&out_new[(size_t)b * NCOL + n]) = ov;
            float s = (ov.x + ov.y) + (ov.z + ov.w);
            s += __shfl_xor(s, 16);
            s += __shfl_xor(s, 32);
            if (lquad == 0)
                out_mean[(size_t)b * HID + (col0 >> 4) + ni] = s * 0.0625f;
        }
    }
}

extern "C" void kernel_launch(void* const* d_in, const int* in_sizes, int n_in,
                              void* d_out, int out_size, void* d_ws, size_t ws_size,
                              hipStream_t stream) {
    const float* x  = (const float*)d_in[0];   // [4096, 256]
    const float* hq = (const float*)d_in[1];   // [4096, 512, 16]
    const float* W  = (const float*)d_in[2];   // [256, 512, 16]

    float* out_mean = (float*)d_out;                          // [4096, 512]
    float* out_new  = (float*)d_out + (size_t)BATCH * HID;    // [4096, 512, 16]

    if (ws_size >= WS_NEED) {
        ushort* whi = (ushort*)d_ws;
        ushort* wlo = whi + W_ELEMS;
        ushort* xhi = wlo + W_ELEMS;
        ushort* xlo = xhi + X_ELEMS;
        prep_w_kernel<<<dim3(NCOL / 256, IN_DIM / 8), 256, 0, stream>>>(W, whi, wlo);
        prep_x_kernel<<<dim3(BATCH / 256, IN_DIM / 8), 256, 0, stream>>>(x, xhi, xlo);
        mqc_main_kernel<<<dim3(BATCH * NCOL / (BM * BN)), 256, 0, stream>>>(
            xhi, xlo, whi, wlo, hq, out_mean, out_new);
    } else {
        mqc_fallback_kernel<<<dim3(BATCH / BM, NCOL / BN), 256, 0, stream>>>(
            x, hq, W, out_mean, out_new);
    }
}

// Round 10
// 146.869 us; speedup vs baseline: 1.2343x; 1.1262x over previous
//
#include <hip/hip_runtime.h>

// Problem dims (fixed by reference)
#define BATCH  4096
#define IN_DIM 256
#define HID    512
#define NCOL   8192            // HID * STATES

// Main tiling: 128x64 block tile, 4 waves stacked on M (32 rows each)
#define BM 128
#define BN 64

typedef __attribute__((ext_vector_type(8))) short bf16x8;
typedef __attribute__((ext_vector_type(4))) float f32x4;
typedef __attribute__((ext_vector_type(4))) float fvec4;   // clang-native, nt-compatible

typedef __attribute__((address_space(1))) const unsigned as1_uint;
typedef __attribute__((address_space(3))) unsigned       as3_uint;

// pack bf16(f0) into low16, bf16(f1) into high16 (truncation) — 1 v_perm_b32
__device__ __forceinline__ uint pack_hi(float f0, float f1) {
    return __builtin_amdgcn_perm(__builtin_bit_cast(uint, f1),
                                 __builtin_bit_cast(uint, f0), 0x07060302u);
}
__device__ __forceinline__ float hi_part(float f) {
    return __builtin_bit_cast(float, __builtin_bit_cast(uint, f) & 0xFFFF0000u);
}
__device__ __forceinline__ float tanh_fast(float x) {
    float e = __builtin_amdgcn_exp2f(x * 2.8853900817779268f); // 2*log2(e)
    float r = __builtin_amdgcn_rcpf(e + 1.0f);
    return __builtin_fmaf(-2.0f, r, 1.0f);
}
// split f[0..7] (k-consecutive) into hi/lo bf16x8 fragments
__device__ __forceinline__ void split8(const float* f, uint4& h, uint4& l) {
    h.x = pack_hi(f[0], f[1]); h.y = pack_hi(f[2], f[3]);
    h.z = pack_hi(f[4], f[5]); h.w = pack_hi(f[6], f[7]);
    l.x = pack_hi(f[0] - hi_part(f[0]), f[1] - hi_part(f[1]));
    l.y = pack_hi(f[2] - hi_part(f[2]), f[3] - hi_part(f[3]));
    l.z = pack_hi(f[4] - hi_part(f[4]), f[5] - hi_part(f[5]));
    l.w = pack_hi(f[6] - hi_part(f[6]), f[7] - hi_part(f[7]));
}

// Workspace layout (ushort elements):
//  whi [0, 2097152)  wlo [2097152, 4194304)   - 8192n x 256k, tiled
//  xhi [4194304, 5242880) xlo [5242880, 6291456) - 4096b x 256k, tiled
// tile layout: plane[((row>>4)*32 + koct)*128 + (row&15)*8 + j], k = koct*8+j
#define W_ELEMS  2097152
#define X_ELEMS  1048576
#define WS_NEED  (12u * 1024u * 1024u)

// ---- prep W: [k][n] f32 -> fragment-ready tiled bf16 hi/lo ----
__global__ __launch_bounds__(256) void prep_w_kernel(
    const float* __restrict__ W, ushort* __restrict__ whi, ushort* __restrict__ wlo)
{
    const int n    = blockIdx.x * 256 + threadIdx.x;   // 0..8191
    const int koct = blockIdx.y;                       // 0..31
    float f[8];
    #pragma unroll
    for (int j = 0; j < 8; ++j)
        f[j] = __builtin_nontemporal_load(&W[(size_t)(koct * 8 + j) * NCOL + n]);
    uint4 h, l;
    split8(f, h, l);
    const size_t o = ((size_t)((n >> 4) * 32 + koct) * 16 + (n & 15)) * 8;
    *(uint4*)(whi + o) = h;
    *(uint4*)(wlo + o) = l;
}

// ---- prep x: [b][k] f32 -> fragment-ready tiled bf16 hi/lo ----
__global__ __launch_bounds__(256) void prep_x_kernel(
    const float* __restrict__ x, ushort* __restrict__ xhi, ushort* __restrict__ xlo)
{
    const int b    = blockIdx.x * 256 + threadIdx.x;   // 0..4095
    const int koct = blockIdx.y;                       // 0..31
    float f[8];
    fvec4 v0 = __builtin_nontemporal_load((const fvec4*)&x[(size_t)b * IN_DIM + koct * 8]);
    fvec4 v1 = __builtin_nontemporal_load((const fvec4*)&x[(size_t)b * IN_DIM + koct * 8 + 4]);
    f[0] = v0.x; f[1] = v0.y; f[2] = v0.z; f[3] = v0.w;
    f[4] = v1.x; f[5] = v1.y; f[6] = v1.z; f[7] = v1.w;
    uint4 h, l;
    split8(f, h, l);
    const size_t o = ((size_t)((b >> 4) * 32 + koct) * 16 + (b & 15)) * 8;
    *(uint4*)(xhi + o) = h;
    *(uint4*)(xlo + o) = l;
}

// ---- main: B fragments staged once per k-chunk into LDS via async DMA ----
// min-waves-per-EU = 4 (VGPR cap 128): round 4 proved 8 (cap 64) forces
// catastrophic scratch spills (+1.2 GB HBM traffic). Do not raise.
// out_mean store must stay CACHED (nt on 4B scalars caused ~8-16x write
// amplification in round 8: WRITE_SIZE 152->275 MB). Do not nt it.
__global__ __launch_bounds__(256, 4) void mqc_main_kernel(
    const ushort* __restrict__ xhi, const ushort* __restrict__ xlo,
    const ushort* __restrict__ whi, const ushort* __restrict__ wlo,
    const float* __restrict__ hq,
    float* __restrict__ out_mean, float* __restrict__ out_new)
{
    // one k-chunk (16 koct = 128 k) of B fragments: 4 ntiles x 16 kl x 16 l16 x 8
    __shared__ ushort sBh[8192], sBl[8192];    // 16 KiB + 16 KiB

    const int t     = threadIdx.x;
    const int lane  = t & 63;
    const int w     = t >> 6;           // wave 0..3 -> rows w*32..w*32+31
    const int lquad = lane >> 4;        // 0..3
    const int l16   = lane & 15;

    // XCD-clustered bijective block mapping (4096 = 8 xcd * 4 rowg * 128 colg)
    const int wgid = blockIdx.x;
    const int xcd  = wgid & 7;
    const int q    = wgid >> 3;
    const int rowg = (xcd << 2) | (q & 3);   // 0..31
    const int colg = q >> 2;                 // 0..127
    const int row0 = rowg * BM;
    const int col0 = colg * BN;
    const int btile0 = (row0 >> 4) + w * 2;
    const int ntile0 = col0 >> 4;

    f32x4 acc[2][4] = {};               // [mi][ni]; D[n][b]: row=n, col=b

    // Stage one k-chunk of B (both planes, 32 KB) via global_load_lds w16.
    // c = itc*4 + w covers 0..31: plane=c>>4, ntile=(c>>2)&3, kslot=c&3.
    // Each DMA: 64 lanes x 16B; lane covers kl=(kslot*4 + lane>>4), l16=lane&15.
    // dest = nt*2048 + kslot*512 + lane*8 (ushorts) == nt*2048 + kl*128 + l16*8.
    #define STAGE(KOCT0) {                                                          \
        _Pragma("unroll")                                                           \
        for (int itc = 0; itc < 8; ++itc) {                                         \
            const int c  = itc * 4 + w;                                             \
            const int nt = (c >> 2) & 3;                                            \
            const int kl = (c & 3) * 4 + (lane >> 4);                               \
            const ushort* srcp = ((c >> 4) ? wlo : whi)                             \
                + ((size_t)(ntile0 + nt) * 32 + (KOCT0) + kl) * 128 + (lane & 15) * 8; \
            ushort* dstp = ((c >> 4) ? sBl : sBh) + nt * 2048 + (c & 3) * 512;      \
            __builtin_amdgcn_global_load_lds((as1_uint*)srcp, (as3_uint*)dstp,      \
                                             16, 0, 0);                             \
        }                                                                           \
    }

    // 4 MFMA k-steps over one staged chunk; A direct from global (L2-hot)
    #define COMPUTE(KOCT0) {                                                        \
        _Pragma("unroll")                                                           \
        for (int sl = 0; sl < 4; ++sl) {                                            \
            const int koct = (KOCT0) + sl * 4 + lquad;                              \
            bf16x8 aH[2], aL[2], bH[4], bL[4];                                      \
            _Pragma("unroll")                                                       \
            for (int mi = 0; mi < 2; ++mi) {                                        \
                const size_t o = ((size_t)(btile0 + mi) * 32 + koct) * 128 + l16 * 8; \
                aH[mi] = *(const bf16x8*)(xhi + o);                                 \
                aL[mi] = *(const bf16x8*)(xlo + o);                                 \
            }                                                                       \
            const int bidx = (sl * 4 + lquad) * 128 + l16 * 8;                      \
            _Pragma("unroll")                                                       \
            for (int ni = 0; ni < 4; ++ni) {                                        \
                bH[ni] = *(const bf16x8*)(sBh + ni * 2048 + bidx);                  \
                bL[ni] = *(const bf16x8*)(sBl + ni * 2048 + bidx);                  \
            }                                                                       \
            _Pragma("unroll")                                                       \
            for (int mi = 0; mi < 2; ++mi)                                          \
                _Pragma("unroll")                                                   \
                for (int ni = 0; ni < 4; ++ni)                                      \
                    acc[mi][ni] = __builtin_amdgcn_mfma_f32_16x16x32_bf16(bH[ni], aH[mi], acc[mi][ni], 0, 0, 0); \
            _Pragma("unroll")                                                       \
            for (int mi = 0; mi < 2; ++mi)                                          \
                _Pragma("unroll")                                                   \
                for (int ni = 0; ni < 4; ++ni)                                      \
                    acc[mi][ni] = __builtin_amdgcn_mfma_f32_16x16x32_bf16(bH[ni], aL[mi], acc[mi][ni], 0, 0, 0); \
            _Pragma("unroll")                                                       \
            for (int mi = 0; mi < 2; ++mi)                                          \
                _Pragma("unroll")                                                   \
                for (int ni = 0; ni < 4; ++ni)                                      \
                    acc[mi][ni] = __builtin_amdgcn_mfma_f32_16x16x32_bf16(bL[ni], aH[mi], acc[mi][ni], 0, 0, 0); \
        }                                                                           \
    }

    STAGE(0);
    __syncthreads();          // drains the DMA (vmcnt) + aligns waves
    COMPUTE(0);
    __syncthreads();          // all reads of chunk 0 done before overwrite
    STAGE(16);
    __syncthreads();
    COMPUTE(16);
    #undef STAGE
    #undef COMPUTE

    // ---- fused epilogue: tanh(C + 0.9*h), nt hq load + nt out_new store,
    //      CACHED out_mean store. D[n][b]: n = col0+ni*16+4*lquad+reg,
    //      b = row0+w*32+mi*16+l16
    #pragma unroll
    for (int mi = 0; mi < 2; ++mi) {
        const int b = row0 + w * 32 + mi * 16 + l16;
        #pragma unroll
        for (int ni = 0; ni < 4; ++ni) {
            const int n = col0 + ni * 16 + lquad * 4;
            const fvec4 hv = __builtin_nontemporal_load((const fvec4*)&hq[(size_t)b * NCOL + n]);
            fvec4 ov;
            ov.x = tanh_fast(__builtin_fmaf(0.9f, hv.x, acc[mi][ni][0]));
            ov.y = tanh_fast(__builtin_fmaf(0.9f, hv.y, acc[mi][ni][1]));
            ov.z = tanh_fast(__builtin_fmaf(0.9f, hv.z, acc[mi][ni][2]));
            ov.w = tanh_fast(__builtin_fmaf(0.9f, hv.w, acc[mi][ni][3]));
            __builtin_nontemporal_store(ov, (fvec4*)&out_new[(size_t)b * NCOL + n]);
            float s = (ov.x + ov.y) + (ov.z + ov.w);
            s += __shfl_xor(s, 16);
            s += __shfl_xor(s, 32);
            if (lquad == 0)
                out_mean[(size_t)b * HID + (col0 >> 4) + ni] = s * 0.0625f;
        }
    }
}

// ================= fallback (round-5 proven kernel, used if ws too small) ======
#define BKF 64
__device__ __forceinline__ int swz(int row, int byteoff) {
    return byteoff ^ ((((row & 7) ^ ((row >> 3) & 7))) << 4);
}
__global__ __launch_bounds__(256, 4) void mqc_fallback_kernel(
    const float* __restrict__ x, const float* __restrict__ hq,
    const float* __restrict__ W,
    float* __restrict__ out_mean, float* __restrict__ out_new)
{
    __shared__ char sB[2 * BN * BKF * 2];
    char* const sB_hi = sB;
    char* const sB_lo = sB + BN * BKF * 2;
    const int t = threadIdx.x, lane = t & 63, w = t >> 6;
    const int lquad = lane >> 4, l16 = lane & 15;
    const int row0 = blockIdx.x * BM, col0 = blockIdx.y * BN;
    const int k0 = (t >> 4) * 4, n0 = (t & 15) * 4;
    f32x4 acc[2][4] = {};
    for (int kt = 0; kt < IN_DIM / BKF; ++kt) {
        float4 ax[2][2][2];
        #pragma unroll
        for (int mi = 0; mi < 2; ++mi)
            #pragma unroll
            for (int ks = 0; ks < 2; ++ks) {
                const float* p = &x[(size_t)(row0 + w * 32 + mi * 16 + l16) * IN_DIM
                                    + kt * BKF + ks * 32 + lquad * 8];
                ax[mi][ks][0] = *(const float4*)(p);
                ax[mi][ks][1] = *(const float4*)(p + 4);
            }
        float4 wrow[4];
        #pragma unroll
        for (int r = 0; r < 4; ++r)
            wrow[r] = *(const float4*)(&W[(size_t)(kt * BKF + k0 + r) * NCOL + col0 + n0]);
        #pragma unroll
        for (int c = 0; c < 4; ++c) {
            const float f0 = ((const float*)&wrow[0])[c];
            const float f1 = ((const float*)&wrow[1])[c];
            const float f2 = ((const float*)&wrow[2])[c];
            const float f3 = ((const float*)&wrow[3])[c];
            uint2 hv2, lv2;
            hv2.x = pack_hi(f0, f1); hv2.y = pack_hi(f2, f3);
            lv2.x = pack_hi(f0 - hi_part(f0), f1 - hi_part(f1));
            lv2.y = pack_hi(f2 - hi_part(f2), f3 - hi_part(f3));
            const int off = swz(n0 + c, (n0 + c) * (BKF * 2) + k0 * 2);
            *(uint2*)(sB_hi + off) = hv2;
            *(uint2*)(sB_lo + off) = lv2;
        }
        __syncthreads();
        #pragma unroll
        for (int ks = 0; ks < 2; ++ks) {
            bf16x8 aH[2], aL[2];
            #pragma unroll
            for (int mi = 0; mi < 2; ++mi) {
                uint4 h, l;
                split8((const float*)&ax[mi][ks][0], h, l);
                aH[mi] = __builtin_bit_cast(bf16x8, h);
                aL[mi] = __builtin_bit_cast(bf16x8, l);
            }
            const int kb = ks * 64 + lquad * 16;
            bf16x8 bH[4], bL[4];
            #pragma unroll
            for (int ni = 0; ni < 4; ++ni) {
                const int row = ni * 16 + l16;
                bH[ni] = *(const bf16x8*)(sB_hi + swz(row, row * (BKF * 2) + kb));
            }
            #pragma unroll
            for (int mi = 0; mi < 2; ++mi)
                #pragma unroll
                for (int ni = 0; ni < 4; ++ni)
                    acc[mi][ni] = __builtin_amdgcn_mfma_f32_16x16x32_bf16(bH[ni], aH[mi], acc[mi][ni], 0, 0, 0);
            #pragma unroll
            for (int mi = 0; mi < 2; ++mi)
                #pragma unroll
                for (int ni = 0; ni < 4; ++ni)
                    acc[mi][ni] = __builtin_amdgcn_mfma_f32_16x16x32_bf16(bH[ni], aL[mi], acc[mi][ni], 0, 0, 0);
            #pragma unroll
            for (int ni = 0; ni < 4; ++ni) {
                const int row = ni * 16 + l16;
                bL[ni] = *(const bf16x8*)(sB_lo + swz(row, row * (BKF * 2) + kb));
            }
            #pragma unroll
            for (int mi = 0; mi < 2; ++mi)
                #pragma unroll
                for (int ni = 0; ni < 4; ++ni)
                    acc[mi][ni] = __builtin_amdgcn_mfma_f32_16x16x32_bf16(bL[ni], aH[mi], acc[mi][ni], 0, 0, 0);
        }
        __syncthreads();
    }
    #pragma unroll
    for (int mi = 0; mi < 2; ++mi) {
        const int b = row0 + w * 32 + mi * 16 + l16;
        #pragma unroll
        for (int ni = 0; ni < 4; ++ni) {
            const int n = col0 + ni * 16 + lquad * 4;
            const float4 hv = *(const float4*)(&hq[(size_t)b * NCOL + n]);
            float4 ov;
            ov.x = tanh_fast(__builtin_fmaf(0.9f, hv.x, acc[mi][ni][0]));
            ov.y = tanh_fast(__builtin_fmaf(0.9f, hv.y, acc[mi][ni][1]));
            ov.z = tanh_fast(__builtin_fmaf(0.9f, hv.z, acc[mi][ni][2]));
            ov.w = tanh_fast(__builtin_fmaf(0.9f, hv.w, acc[mi][ni][3]));
            *(float4*)(&out_new[(size_t)b * NCOL + n]) = ov;
            float s = (ov.x + ov.y) + (ov.z + ov.w);
            s += __shfl_xor(s, 16);
            s += __shfl_xor(s, 32);
            if (lquad == 0)
                out_mean[(size_t)b * HID + (col0 >> 4) + ni] = s * 0.0625f;
        }
    }
}

extern "C" void kernel_launch(void* const* d_in, const int* in_sizes, int n_in,
                              void* d_out, int out_size, void* d_ws, size_t ws_size,
                              hipStream_t stream) {
    const float* x  = (const float*)d_in[0];   // [4096, 256]
    const float* hq = (const float*)d_in[1];   // [4096, 512, 16]
    const float* W  = (const float*)d_in[2];   // [256, 512, 16]

    float* out_mean = (float*)d_out;                          // [4096, 512]
    float* out_new  = (float*)d_out + (size_t)BATCH * HID;    // [4096, 512, 16]

    if (ws_size >= WS_NEED) {
        ushort* whi = (ushort*)d_ws;
        ushort* wlo = whi + W_ELEMS;
        ushort* xhi = wlo + W_ELEMS;
        ushort* xlo = xhi + X_ELEMS;
        prep_w_kernel<<<dim3(NCOL / 256, IN_DIM / 8), 256, 0, stream>>>(W, whi, wlo);
        prep_x_kernel<<<dim3(BATCH / 256, IN_DIM / 8), 256, 0, stream>>>(x, xhi, xlo);
        mqc_main_kernel<<<dim3(BATCH * NCOL / (BM * BN)), 256, 0, stream>>>(
            xhi, xlo, whi, wlo, hq, out_mean, out_new);
    } else {
        mqc_fallback_kernel<<<dim3(BATCH / BM, NCOL / BN), 256, 0, stream>>>(
            x, hq, W, out_mean, out_new);
    }
}

// Round 11
// 93.036 us; speedup vs baseline: 1.9485x; 1.5786x over previous
//
#include <hip/hip_runtime.h>

// Problem dims (fixed by reference)
#define BATCH  4096
#define IN_DIM 256
#define HID    512
#define NCOL   8192            // HID * STATES

// Main tiling: 128x64 block tile, 4 waves stacked on M (32 rows each)
#define BM 128
#define BN 64

typedef __attribute__((ext_vector_type(8))) short bf16x8;
typedef __attribute__((ext_vector_type(4))) float f32x4;
typedef __attribute__((ext_vector_type(4))) float fvec4;   // clang-native, nt-compatible

typedef __attribute__((address_space(1))) const unsigned as1_uint;
typedef __attribute__((address_space(3))) unsigned       as3_uint;

// pack bf16(f0) into low16, bf16(f1) into high16 (truncation) — 1 v_perm_b32
__device__ __forceinline__ uint pack_hi(float f0, float f1) {
    return __builtin_amdgcn_perm(__builtin_bit_cast(uint, f1),
                                 __builtin_bit_cast(uint, f0), 0x07060302u);
}
__device__ __forceinline__ float hi_part(float f) {
    return __builtin_bit_cast(float, __builtin_bit_cast(uint, f) & 0xFFFF0000u);
}
__device__ __forceinline__ float tanh_fast(float x) {
    float e = __builtin_amdgcn_exp2f(x * 2.8853900817779268f); // 2*log2(e)
    float r = __builtin_amdgcn_rcpf(e + 1.0f);
    return __builtin_fmaf(-2.0f, r, 1.0f);
}
// split f[0..7] (k-consecutive) into hi/lo bf16x8 fragments
__device__ __forceinline__ void split8(const float* f, uint4& h, uint4& l) {
    h.x = pack_hi(f[0], f[1]); h.y = pack_hi(f[2], f[3]);
    h.z = pack_hi(f[4], f[5]); h.w = pack_hi(f[6], f[7]);
    l.x = pack_hi(f[0] - hi_part(f[0]), f[1] - hi_part(f[1]));
    l.y = pack_hi(f[2] - hi_part(f[2]), f[3] - hi_part(f[3]));
    l.z = pack_hi(f[4] - hi_part(f[4]), f[5] - hi_part(f[5]));
    l.w = pack_hi(f[6] - hi_part(f[6]), f[7] - hi_part(f[7]));
}

// Workspace layout (ushort elements):
//  whi [0, 2097152)  wlo [2097152, 4194304)   - 8192n x 256k, tiled
//  xhi [4194304, 5242880) xlo [5242880, 6291456) - 4096b x 256k, tiled
// tile layout: plane[((row>>4)*32 + koct)*128 + (row&15)*8 + j], k = koct*8+j
#define W_ELEMS  2097152
#define X_ELEMS  1048576
#define WS_NEED  (12u * 1024u * 1024u)

// ---- prep W: [k][n] f32 -> fragment-ready tiled bf16 hi/lo ----
__global__ __launch_bounds__(256) void prep_w_kernel(
    const float* __restrict__ W, ushort* __restrict__ whi, ushort* __restrict__ wlo)
{
    const int n    = blockIdx.x * 256 + threadIdx.x;   // 0..8191
    const int koct = blockIdx.y;                       // 0..31
    float f[8];
    #pragma unroll
    for (int j = 0; j < 8; ++j)
        f[j] = __builtin_nontemporal_load(&W[(size_t)(koct * 8 + j) * NCOL + n]);
    uint4 h, l;
    split8(f, h, l);
    const size_t o = ((size_t)((n >> 4) * 32 + koct) * 16 + (n & 15)) * 8;
    *(uint4*)(whi + o) = h;
    *(uint4*)(wlo + o) = l;
}

// ---- prep x: [b][k] f32 -> fragment-ready tiled bf16 hi/lo ----
__global__ __launch_bounds__(256) void prep_x_kernel(
    const float* __restrict__ x, ushort* __restrict__ xhi, ushort* __restrict__ xlo)
{
    const int b    = blockIdx.x * 256 + threadIdx.x;   // 0..4095
    const int koct = blockIdx.y;                       // 0..31
    float f[8];
    fvec4 v0 = __builtin_nontemporal_load((const fvec4*)&x[(size_t)b * IN_DIM + koct * 8]);
    fvec4 v1 = __builtin_nontemporal_load((const fvec4*)&x[(size_t)b * IN_DIM + koct * 8 + 4]);
    f[0] = v0.x; f[1] = v0.y; f[2] = v0.z; f[3] = v0.w;
    f[4] = v1.x; f[5] = v1.y; f[6] = v1.z; f[7] = v1.w;
    uint4 h, l;
    split8(f, h, l);
    const size_t o = ((size_t)((b >> 4) * 32 + koct) * 16 + (b & 15)) * 8;
    *(uint4*)(xhi + o) = h;
    *(uint4*)(xlo + o) = l;
}

// ---- main: B via LDS DMA, A via register-prefetch ping-pong ----
// __launch_bounds__(256,3): unified VGPR+AGPR cap ~170. Round 10 proved the
// (256,4)=128 cap (minus 32 acc AGPRs) made the compiler sink every prefetch
// (VGPR_Count stuck at 52) while real occupancy was 3 blocks/CU anyway.
// Round 4 proved (256,8) spills catastrophically. Do not raise past 4.
// out_mean store must stay CACHED (nt on 4B scalars caused ~8-16x write
// amplification in round 8: WRITE_SIZE 152->275 MB). Do not nt it.
// hq loads CACHED (streams through 256MB L3); out_new store stays nt.
__global__ __launch_bounds__(256, 3) void mqc_main_kernel(
    const ushort* __restrict__ xhi, const ushort* __restrict__ xlo,
    const ushort* __restrict__ whi, const ushort* __restrict__ wlo,
    const float* __restrict__ hq,
    float* __restrict__ out_mean, float* __restrict__ out_new)
{
    // one k-chunk (16 koct = 128 k) of B fragments: 4 ntiles x 16 kl x 16 l16 x 8
    __shared__ ushort sBh[8192], sBl[8192];    // 16 KiB + 16 KiB

    const int t     = threadIdx.x;
    const int lane  = t & 63;
    const int w     = t >> 6;           // wave 0..3 -> rows w*32..w*32+31
    const int lquad = lane >> 4;        // 0..3
    const int l16   = lane & 15;

    // XCD-clustered bijective block mapping (4096 = 8 xcd * 4 rowg * 128 colg)
    const int wgid = blockIdx.x;
    const int xcd  = wgid & 7;
    const int q    = wgid >> 3;
    const int rowg = (xcd << 2) | (q & 3);   // 0..31
    const int colg = q >> 2;                 // 0..127
    const int row0 = rowg * BM;
    const int col0 = colg * BN;
    const int btile0 = (row0 >> 4) + w * 2;
    const int ntile0 = col0 >> 4;

    f32x4 acc[2][4] = {};               // [mi][ni]; D[n][b]: row=n, col=b

    // Stage one k-chunk of B (both planes, 32 KB) via global_load_lds w16.
    #define STAGE(KOCT0) {                                                          \
        _Pragma("unroll")                                                           \
        for (int itc = 0; itc < 8; ++itc) {                                         \
            const int c  = itc * 4 + w;                                             \
            const int nt = (c >> 2) & 3;                                            \
            const int kl = (c & 3) * 4 + (lane >> 4);                               \
            const ushort* srcp = ((c >> 4) ? wlo : whi)                             \
                + ((size_t)(ntile0 + nt) * 32 + (KOCT0) + kl) * 128 + (lane & 15) * 8; \
            ushort* dstp = ((c >> 4) ? sBl : sBh) + nt * 2048 + (c & 3) * 512;      \
            __builtin_amdgcn_global_load_lds((as1_uint*)srcp, (as3_uint*)dstp,      \
                                             16, 0, 0);                             \
        }                                                                           \
    }

    // prefetch A fragments for 2 k-steps (SL0, SL0+1) of chunk KOCT0 into regs
    #define APREF(AH, AL, KOCT0, SL0) {                                             \
        _Pragma("unroll")                                                           \
        for (int s = 0; s < 2; ++s) {                                               \
            const int koct = (KOCT0) + ((SL0) + s) * 4 + lquad;                     \
            _Pragma("unroll")                                                       \
            for (int mi = 0; mi < 2; ++mi) {                                        \
                const size_t o = ((size_t)(btile0 + mi) * 32 + koct) * 128 + l16 * 8; \
                AH[s][mi] = *(const bf16x8*)(xhi + o);                              \
                AL[s][mi] = *(const bf16x8*)(xlo + o);                              \
            }                                                                       \
        }                                                                           \
    }

    // 2 MFMA k-steps (SL0, SL0+1) using prefetched A regs + staged B in LDS
    #define KSTEP2(AH, AL, SL0) {                                                   \
        _Pragma("unroll")                                                           \
        for (int s = 0; s < 2; ++s) {                                               \
            const int bidx = (((SL0) + s) * 4 + lquad) * 128 + l16 * 8;             \
            bf16x8 bH[4], bL[4];                                                    \
            _Pragma("unroll")                                                       \
            for (int ni = 0; ni < 4; ++ni) {                                        \
                bH[ni] = *(const bf16x8*)(sBh + ni * 2048 + bidx);                  \
                bL[ni] = *(const bf16x8*)(sBl + ni * 2048 + bidx);                  \
            }                                                                       \
            _Pragma("unroll")                                                       \
            for (int mi = 0; mi < 2; ++mi)                                          \
                _Pragma("unroll")                                                   \
                for (int ni = 0; ni < 4; ++ni)                                      \
                    acc[mi][ni] = __builtin_amdgcn_mfma_f32_16x16x32_bf16(bH[ni], AH[s][mi], acc[mi][ni], 0, 0, 0); \
            _Pragma("unroll")                                                       \
            for (int mi = 0; mi < 2; ++mi)                                          \
                _Pragma("unroll")                                                   \
                for (int ni = 0; ni < 4; ++ni)                                      \
                    acc[mi][ni] = __builtin_amdgcn_mfma_f32_16x16x32_bf16(bH[ni], AL[s][mi], acc[mi][ni], 0, 0, 0); \
            _Pragma("unroll")                                                       \
            for (int mi = 0; mi < 2; ++mi)                                          \
                _Pragma("unroll")                                                   \
                for (int ni = 0; ni < 4; ++ni)                                      \
                    acc[mi][ni] = __builtin_amdgcn_mfma_f32_16x16x32_bf16(bL[ni], AH[s][mi], acc[mi][ni], 0, 0, 0); \
        }                                                                           \
    }

    bf16x8 AaH[2][2], AaL[2][2], AbH[2][2], AbL[2][2];
    fvec4 hv[2][4];

    // ---- chunk 0 (koct 0..15) ----
    STAGE(0);
    APREF(AaH, AaL, 0, 0);          // A for ksteps 0,1 — in flight with DMA
    __syncthreads();                // drains DMA + A loads
    APREF(AbH, AbL, 0, 2);          // A for ksteps 2,3 — hidden under KSTEP2
    KSTEP2(AaH, AaL, 0);
    KSTEP2(AbH, AbL, 2);
    __syncthreads();                // chunk-0 LDS reads done before overwrite
    // ---- chunk 1 (koct 16..31) ----
    STAGE(16);
    APREF(AaH, AaL, 16, 0);
    __syncthreads();
    APREF(AbH, AbL, 16, 2);
    KSTEP2(AaH, AaL, 0);
    // epilogue hq prefetch (cached): covered by the remaining 48 MFMAs
    #pragma unroll
    for (int mi = 0; mi < 2; ++mi) {
        const int b = row0 + w * 32 + mi * 16 + l16;
        #pragma unroll
        for (int ni = 0; ni < 4; ++ni) {
            const int n = col0 + ni * 16 + lquad * 4;
            hv[mi][ni] = *(const fvec4*)&hq[(size_t)b * NCOL + n];
        }
    }
    KSTEP2(AbH, AbL, 2);
    #undef STAGE
    #undef APREF
    #undef KSTEP2

    // ---- fused epilogue: tanh(C + 0.9*h), nt out_new store, cached out_mean.
    //      D[n][b]: n = col0+ni*16+4*lquad+reg, b = row0+w*32+mi*16+l16
    #pragma unroll
    for (int mi = 0; mi < 2; ++mi) {
        const int b = row0 + w * 32 + mi * 16 + l16;
        #pragma unroll
        for (int ni = 0; ni < 4; ++ni) {
            const int n = col0 + ni * 16 + lquad * 4;
            fvec4 ov;
            ov.x = tanh_fast(__builtin_fmaf(0.9f, hv[mi][ni].x, acc[mi][ni][0]));
            ov.y = tanh_fast(__builtin_fmaf(0.9f, hv[mi][ni].y, acc[mi][ni][1]));
            ov.z = tanh_fast(__builtin_fmaf(0.9f, hv[mi][ni].z, acc[mi][ni][2]));
            ov.w = tanh_fast(__builtin_fmaf(0.9f, hv[mi][ni].w, acc[mi][ni][3]));
            __builtin_nontemporal_store(ov, (fvec4*)&out_new[(size_t)b * NCOL + n]);
            float s = (ov.x + ov.y) + (ov.z + ov.w);
            s += __shfl_xor(s, 16);
            s += __shfl_xor(s, 32);
            if (lquad == 0)
                out_mean[(size_t)b * HID + (col0 >> 4) + ni] = s * 0.0625f;
        }
    }
}

// ================= fallback (round-5 proven kernel, used if ws too small) ======
#define BKF 64
__device__ __forceinline__ int swz(int row, int byteoff) {
    return byteoff ^ ((((row & 7) ^ ((row >> 3) & 7))) << 4);
}
__global__ __launch_bounds__(256, 4) void mqc_fallback_kernel(
    const float* __restrict__ x, const float* __restrict__ hq,
    const float* __restrict__ W,
    float* __restrict__ out_mean, float* __restrict__ out_new)
{
    __shared__ char sB[2 * BN * BKF * 2];
    char* const sB_hi = sB;
    char* const sB_lo = sB + BN * BKF * 2;
    const int t = threadIdx.x, lane = t & 63, w = t >> 6;
    const int lquad = lane >> 4, l16 = lane & 15;
    const int row0 = blockIdx.x * BM, col0 = blockIdx.y * BN;
    const int k0 = (t >> 4) * 4, n0 = (t & 15) * 4;
    f32x4 acc[2][4] = {};
    for (int kt = 0; kt < IN_DIM / BKF; ++kt) {
        float4 ax[2][2][2];
        #pragma unroll
        for (int mi = 0; mi < 2; ++mi)
            #pragma unroll
            for (int ks = 0; ks < 2; ++ks) {
                const float* p = &x[(size_t)(row0 + w * 32 + mi * 16 + l16) * IN_DIM
                                    + kt * BKF + ks * 32 + lquad * 8];
                ax[mi][ks][0] = *(const float4*)(p);
                ax[mi][ks][1] = *(const float4*)(p + 4);
            }
        float4 wrow[4];
        #pragma unroll
        for (int r = 0; r < 4; ++r)
            wrow[r] = *(const float4*)(&W[(size_t)(kt * BKF + k0 + r) * NCOL + col0 + n0]);
        #pragma unroll
        for (int c = 0; c < 4; ++c) {
            const float f0 = ((const float*)&wrow[0])[c];
            const float f1 = ((const float*)&wrow[1])[c];
            const float f2 = ((const float*)&wrow[2])[c];
            const float f3 = ((const float*)&wrow[3])[c];
            uint2 hv2, lv2;
            hv2.x = pack_hi(f0, f1); hv2.y = pack_hi(f2, f3);
            lv2.x = pack_hi(f0 - hi_part(f0), f1 - hi_part(f1));
            lv2.y = pack_hi(f2 - hi_part(f2), f3 - hi_part(f3));
            const int off = swz(n0 + c, (n0 + c) * (BKF * 2) + k0 * 2);
            *(uint2*)(sB_hi + off) = hv2;
            *(uint2*)(sB_lo + off) = lv2;
        }
        __syncthreads();
        #pragma unroll
        for (int ks = 0; ks < 2; ++ks) {
            bf16x8 aH[2], aL[2];
            #pragma unroll
            for (int mi = 0; mi < 2; ++mi) {
                uint4 h, l;
                split8((const float*)&ax[mi][ks][0], h, l);
                aH[mi] = __builtin_bit_cast(bf16x8, h);
                aL[mi] = __builtin_bit_cast(bf16x8, l);
            }
            const int kb = ks * 64 + lquad * 16;
            bf16x8 bH[4], bL[4];
            #pragma unroll
            for (int ni = 0; ni < 4; ++ni) {
                const int row = ni * 16 + l16;
                bH[ni] = *(const bf16x8*)(sB_hi + swz(row, row * (BKF * 2) + kb));
            }
            #pragma unroll
            for (int mi = 0; mi < 2; ++mi)
                #pragma unroll
                for (int ni = 0; ni < 4; ++ni)
                    acc[mi][ni] = __builtin_amdgcn_mfma_f32_16x16x32_bf16(bH[ni], aH[mi], acc[mi][ni], 0, 0, 0);
            #pragma unroll
            for (int mi = 0; mi < 2; ++mi)
                #pragma unroll
                for (int ni = 0; ni < 4; ++ni)
                    acc[mi][ni] = __builtin_amdgcn_mfma_f32_16x16x32_bf16(bH[ni], aL[mi], acc[mi][ni], 0, 0, 0);
            #pragma unroll
            for (int ni = 0; ni < 4; ++ni) {
                const int row = ni * 16 + l16;
                bL[ni] = *(const bf16x8*)(sB_lo + swz(row, row * (BKF * 2) + kb));
            }
            #pragma unroll
            for (int mi = 0; mi < 2; ++mi)
                #pragma unroll
                for (int ni = 0; ni < 4; ++ni)
                    acc[mi][ni] = __builtin_amdgcn_mfma_f32_16x16x32_bf16(bL[ni], aH[mi], acc[mi][ni], 0, 0, 0);
        }
        __syncthreads();
    }
    #pragma unroll
    for (int mi = 0; mi < 2; ++mi) {
        const int b = row0 + w * 32 + mi * 16 + l16;
        #pragma unroll
        for (int ni = 0; ni < 4; ++ni) {
            const int n = col0 + ni * 16 + lquad * 4;
            const float4 hv = *(const float4*)(&hq[(size_t)b * NCOL + n]);
            float4 ov;
            ov.x = tanh_fast(__builtin_fmaf(0.9f, hv.x, acc[mi][ni][0]));
            ov.y = tanh_fast(__builtin_fmaf(0.9f, hv.y, acc[mi][ni][1]));
            ov.z = tanh_fast(__builtin_fmaf(0.9f, hv.z, acc[mi][ni][2]));
            ov.w = tanh_fast(__builtin_fmaf(0.9f, hv.w, acc[mi][ni][3]));
            *(float4*)(&out_new[(size_t)b * NCOL + n]) = ov;
            float s = (ov.x + ov.y) + (ov.z + ov.w);
            s += __shfl_xor(s, 16);
            s += __shfl_xor(s, 32);
            if (lquad == 0)
                out_mean[(size_t)b * HID + (col0 >> 4) + ni] = s * 0.0625f;
        }
    }
}

extern "C" void kernel_launch(void* const* d_in, const int* in_sizes, int n_in,
                              void* d_out, int out_size, void* d_ws, size_t ws_size,
                              hipStream_t stream) {
    const float* x  = (const float*)d_in[0];   // [4096, 256]
    const float* hq = (const float*)d_in[1];   // [4096, 512, 16]
    const float* W  = (const float*)d_in[2];   // [256, 512, 16]

    float* out_mean = (float*)d_out;                          // [4096, 512]
    float* out_new  = (float*)d_out + (size_t)BATCH * HID;    // [4096, 512, 16]

    if (ws_size >= WS_NEED) {
        ushort* whi = (ushort*)d_ws;
        ushort* wlo = whi + W_ELEMS;
        ushort* xhi = wlo + W_ELEMS;
        ushort* xlo = xhi + X_ELEMS;
        prep_w_kernel<<<dim3(NCOL / 256, IN_DIM / 8), 256, 0, stream>>>(W, whi, wlo);
        prep_x_kernel<<<dim3(BATCH / 256, IN_DIM / 8), 256, 0, stream>>>(x, xhi, xlo);
        mqc_main_kernel<<<dim3(BATCH * NCOL / (BM * BN)), 256, 0, stream>>>(
            xhi, xlo, whi, wlo, hq, out_mean, out_new);
    } else {
        mqc_fallback_kernel<<<dim3(BATCH / BM, NCOL / BN), 256, 0, stream>>>(
            x, hq, W, out_mean, out_new);
    }
}